// Round 5
// baseline (228.008 us; speedup 1.0000x reference)
//
#include <hip/hip_runtime.h>
#include <hip/hip_bf16.h>

#define T_STEPS 512
#define BATCH 32
#define NST 64
#define DIM 1024
#define LOG2E 1.44269504f

typedef _Float16 f16x8 __attribute__((ext_vector_type(8)));
typedef _Float16 f16x4 __attribute__((ext_vector_type(4)));
typedef float f32x4 __attribute__((ext_vector_type(4)));

__device__ __forceinline__ void gl_lds16(const void* g, void* l) {
  __builtin_amdgcn_global_load_lds(
      (const __attribute__((address_space(1))) void*)g,
      (__attribute__((address_space(3))) void*)l, 16, 0, 0);
}

// ---------------- W concat + fp16 convert ----------------
// Wc[256][1024] fp16, row order [Wk | Wq | Wv | Wa].
__global__ __launch_bounds__(256) void wconv(
    const float* __restrict__ Wk, const float* __restrict__ Wv,
    const float* __restrict__ Wq, const float* __restrict__ Wa,
    _Float16* __restrict__ Wc) {
  const int n = blockIdx.x;
  const int g = n >> 6, r = n & 63;
  const float* W = (g == 0) ? Wk : (g == 1) ? Wq : (g == 2) ? Wv : Wa;
  float4 v = *(const float4*)(W + (size_t)r * DIM + threadIdx.x * 4);
  f16x4 h = {(_Float16)v.x, (_Float16)v.y, (_Float16)v.z, (_Float16)v.w};
  *(f16x4*)(Wc + (size_t)n * DIM + threadIdx.x * 4) = h;
}

// ---------------- Projection GEMM, k-split 2 ----------------
// Block (bx, kh): 64m x 256n tile, K-range [kh*512, kh*512+512), BK=32.
// 4 waves (2m x 2n), wave tile 32m x 128n. ONE barrier per kt; prefetch
// (A global regs + B global_load_lds) issued AFTER the barrier so the next
// barrier's vmcnt(0) drain overlaps this iteration's compute; 2 blocks/CU
// cover each other's residual drain. Partials written f16 to P + kh*16384*256.
__global__ __launch_bounds__(256) void proj_gemm(
    const float* __restrict__ x, const _Float16* __restrict__ Wc,
    _Float16* __restrict__ P) {
  const int m0 = blockIdx.x * 64;
  const int kh = blockIdx.y;
  const int kbase = kh * 512;
  const int tid = threadIdx.x;
  const int lane = tid & 63, wv = tid >> 6;
  const int wm = wv >> 1, wn = wv & 1;
  const int fm = lane & 15, fq = lane >> 4;

  __shared__ __align__(16) _Float16 Al[2][64 * 40];
  __shared__ __align__(16) _Float16 Bl[2][256 * 32];

  f32x4 acc[2][8];
#pragma unroll
  for (int mi = 0; mi < 2; ++mi)
#pragma unroll
    for (int ni = 0; ni < 8; ++ni) acc[mi][ni] = (f32x4){0.f, 0.f, 0.f, 0.f};

  // B staging: wave wv covers rows [wv*64, +64), 4 instrs of 16 rows.
  // XOR-swizzled k-chunk so frag reads stay bank-balanced (R4-verified).
  const int bchunk = (lane & 3) ^ ((lane >> 3) & 3);
  const _Float16* gB = Wc + (size_t)(wv * 64 + (lane >> 2)) * DIM + kbase + bchunk * 8;
  _Float16* lB = &Bl[0][0] + (size_t)wv * 64 * 32 + lane * 8;  // + buf*8192 + j*512

  // A staging: thread loads 8 floats of one x row per kt.
  const int arow = tid >> 2;
  const int acol = (tid & 3) * 8;
  const float* gA = x + (size_t)(m0 + arow) * DIM + kbase + acol;

#define STAGE_B(buf, koff)                                          \
  {                                                                 \
    _Pragma("unroll") for (int j = 0; j < 4; ++j)                   \
        gl_lds16(gB + (size_t)j * 16 * DIM + (koff),                \
                 lB + (size_t)(buf) * 8192 + j * 512);              \
  }
  float4 xa, xb;
#define LOAD_A(koff)                          \
  {                                           \
    xa = *(const float4*)(gA + (koff));       \
    xb = *(const float4*)(gA + (koff) + 4);   \
  }

  LOAD_A(0);
  STAGE_B(0, 0);
  for (int kt = 0; kt < 16; ++kt) {
    const int cur = kt & 1;
    f16x8 ah;
    ah[0] = (_Float16)xa.x; ah[1] = (_Float16)xa.y;
    ah[2] = (_Float16)xa.z; ah[3] = (_Float16)xa.w;
    ah[4] = (_Float16)xb.x; ah[5] = (_Float16)xb.y;
    ah[6] = (_Float16)xb.z; ah[7] = (_Float16)xb.w;
    *(f16x8*)&Al[cur][arow * 40 + acol] = ah;
    __syncthreads();  // drains: B[cur] gl_lds complete; A write visible
    if (kt + 1 < 16) {
      LOAD_A((kt + 1) * 32);
      STAGE_B(cur ^ 1, (kt + 1) * 32);  // in flight across this kt's compute
    }
    f16x8 afr[2], bfr[8];
#pragma unroll
    for (int mi = 0; mi < 2; ++mi)
      afr[mi] = *(const f16x8*)&Al[cur][(wm * 32 + mi * 16 + fm) * 40 + fq * 8];
    const int slot = fq ^ ((fm >> 1) & 3);
#pragma unroll
    for (int ni = 0; ni < 8; ++ni) {
      const int row = wn * 128 + ni * 16 + fm;
      bfr[ni] = *(const f16x8*)&Bl[cur][row * 32 + slot * 8];
    }
#pragma unroll
    for (int mi = 0; mi < 2; ++mi)
#pragma unroll
      for (int ni = 0; ni < 8; ++ni)
        acc[mi][ni] =
            __builtin_amdgcn_mfma_f32_16x16x32_f16(afr[mi], bfr[ni], acc[mi][ni], 0, 0, 0);
  }
#undef STAGE_B
#undef LOAD_A

  // C/D: col = lane&15 (n), row = (lane>>4)*4 + reg (m). v/ax cols interleaved.
  _Float16* Pout = P + (size_t)kh * 16384 * 256;
#pragma unroll
  for (int mi = 0; mi < 2; ++mi)
#pragma unroll
    for (int ni = 0; ni < 8; ++ni) {
      const int gcol = wn * 128 + ni * 16 + fm;
      const int pcol = gcol < 128 ? gcol
                     : (gcol < 192 ? 128 + 2 * (gcol - 128) : 129 + 2 * (gcol - 192));
#pragma unroll
      for (int r = 0; r < 4; ++r) {
        const int grow = m0 + wm * 32 + mi * 16 + fq * 4 + r;
        Pout[(size_t)grow * 256 + pcol] = (_Float16)acc[mi][ni][r];
      }
    }
}

// ---------------- Sequential scan ----------------
// 128 blocks = (b, 16-row group), 256 threads = 16 rows x 16 lanes; thread
// owns S[b][r][4c..4c+3]. Three INDEPENDENT 16-lane DPP all-reduces per step
// (S.k, S.q, k.q) run concurrently; h = al*(S.q) + cc*(k.q) so no reduce
// follows the state update. lbuf holds f32 (k-half partials added at staging)
// so the inner loop has zero converts. Prefetch ring depth 2.
__device__ __forceinline__ float red16(float x) {
  int v = __builtin_amdgcn_update_dpp(0, __float_as_int(x), 0xB1, 0xF, 0xF, true);
  x += __int_as_float(v);
  v = __builtin_amdgcn_update_dpp(0, __float_as_int(x), 0x4E, 0xF, 0xF, true);
  x += __int_as_float(v);
  v = __builtin_amdgcn_update_dpp(0, __float_as_int(x), 0x124, 0xF, 0xF, true);
  x += __int_as_float(v);
  v = __builtin_amdgcn_update_dpp(0, __float_as_int(x), 0x128, 0xF, 0xF, true);
  x += __int_as_float(v);
  return x;
}

__global__ __launch_bounds__(256) void scan_kernel(
    const _Float16* __restrict__ P0, const _Float16* __restrict__ P1,
    const float* __restrict__ S0, const float* __restrict__ d_alpha,
    const float* __restrict__ b_alpha, float* __restrict__ out,
    float* __restrict__ Sout) {
  const int b = blockIdx.x >> 2;
  const int rg = blockIdx.x & 3;
  const int tid = threadIdx.x;
  const int c = tid & 15;
  const int r = rg * 16 + (tid >> 4);
  const int j0 = c * 4;

  __shared__ __align__(16) float lbuf[2 * 2048];  // 2 chunks x 8 steps x 256 f32

  float s[4];
  {
    float4 v = *(const float4*)(S0 + ((size_t)b * NST + r) * NST + j0);
    s[0] = v.x; s[1] = v.y; s[2] = v.z; s[3] = v.w;
  }
  const float da = d_alpha[r];
  const float ba = b_alpha[r];
  const float mda = -da * LOG2E;

  // chunk staging: thread covers 8 halves of step (tid>>5) at elems (tid&31)*8
  const int lidx = (tid >> 5) * 256 + (tid & 31) * 8;
#define GOFF(ch) (((size_t)((ch) * 8 + (tid >> 5)) * BATCH + b) * 256 + (tid & 31) * 8)

  f16x8 rA0, rA1;
#define CVWR(slot)                                                   \
  {                                                                  \
    float4 w0, w1;                                                   \
    w0.x = (float)rA0[0] + (float)rA1[0];                            \
    w0.y = (float)rA0[1] + (float)rA1[1];                            \
    w0.z = (float)rA0[2] + (float)rA1[2];                            \
    w0.w = (float)rA0[3] + (float)rA1[3];                            \
    w1.x = (float)rA0[4] + (float)rA1[4];                            \
    w1.y = (float)rA0[5] + (float)rA1[5];                            \
    w1.z = (float)rA0[6] + (float)rA1[6];                            \
    w1.w = (float)rA0[7] + (float)rA1[7];                            \
    *(float4*)(lbuf + (slot) * 2048 + lidx) = w0;                    \
    *(float4*)(lbuf + (slot) * 2048 + lidx + 4) = w1;                \
  }

  rA0 = *(const f16x8*)(P0 + GOFF(0)); rA1 = *(const f16x8*)(P1 + GOFF(0));
  CVWR(0);
  rA0 = *(const f16x8*)(P0 + GOFF(1)); rA1 = *(const f16x8*)(P1 + GOFF(1));
  CVWR(1);
  rA0 = *(const f16x8*)(P0 + GOFF(2)); rA1 = *(const f16x8*)(P1 + GOFF(2));
  __syncthreads();

  float4 kf[4], qf[4];
  float2 va[4];
#define PREF(tn)                                                             \
  {                                                                          \
    const int pp = (tn) & 3;                                                 \
    const float* Pn = lbuf + (((tn) >> 3) & 1) * 2048 + ((tn) & 7) * 256;    \
    kf[pp] = *(const float4*)(Pn + j0);                                      \
    qf[pp] = *(const float4*)(Pn + 64 + j0);                                 \
    va[pp] = *(const float2*)(Pn + 128 + 2 * r);                             \
  }

  PREF(0);
  PREF(1);
  for (int ch = 0; ch < 64; ++ch) {
#pragma unroll
    for (int si = 0; si < 8; ++si) {
      const int t = ch * 8 + si;
      const int p = t & 3;
      if (t + 2 < T_STEPS) PREF(t + 2);

      const float k0 = kf[p].x, k1 = kf[p].y, k2 = kf[p].z, k3 = kf[p].w;
      const float q0 = qf[p].x, q1 = qf[p].y, q2 = qf[p].z, q3 = qf[p].w;
      const float vi = va[p].x;
      const float zcv = (va[p].y + ba) * (-LOG2E);  // off the rr chain

      // three independent partial dots -> three concurrent 16-lane reduces
      float pa = fmaf(s[0], k0, s[1] * k1);
      float pb = fmaf(s[2], k2, s[3] * k3);
      float ua = fmaf(s[0], q0, s[1] * q1);
      float ub = fmaf(s[2], q2, s[3] * q3);
      float ka = fmaf(k0, q0, k1 * q1);
      float kb = fmaf(k2, q2, k3 * q3);
      const float rr = red16(pa + pb);
      const float uu = red16(ua + ub);
      const float kq = red16(ka + kb);

      // e = exp(-z) = 2^(rr*(-da*log2e) + (ax+ba)*(-log2e)); clamp |.| <= 45
      float tt = fmaf(rr, mda, zcv);
      tt = fminf(fmaxf(tt, -45.f), 45.f);
      const float e = exp2f(tt);
      const float al = __builtin_amdgcn_rcpf(1.f + e);  // sigmoid(z)
      const float cc = (e * vi) * al;                   // (1-al)*v

      s[0] = fmaf(al, s[0], cc * k0);
      s[1] = fmaf(al, s[1], cc * k1);
      s[2] = fmaf(al, s[2], cc * k2);
      s[3] = fmaf(al, s[3], cc * k3);

      const float h = fmaf(al, uu, cc * kq);  // = S_new . q (exact reorder)
      if (c == 0) {
        const float sg = __builtin_amdgcn_rcpf(1.f + __expf(-h));
        out[((size_t)t * BATCH + b) * NST + r] = h * h * sg;
      }
    }
    if (ch + 2 < 64) {
      __syncthreads();   // reads of chunk ch done
      CVWR(ch & 1);      // stage chunk ch+2
      if (ch + 3 < 64) {
        rA0 = *(const f16x8*)(P0 + GOFF(ch + 3));
        rA1 = *(const f16x8*)(P1 + GOFF(ch + 3));
      }
      __syncthreads();   // visible before chunk ch+2 read
    }
  }
#undef PREF
#undef CVWR
#undef GOFF

  float4 o = {s[0], s[1], s[2], s[3]};
  *(float4*)(Sout + ((size_t)b * NST + r) * NST + j0) = o;
}

extern "C" void kernel_launch(void* const* d_in, const int* in_sizes, int n_in,
                              void* d_out, int out_size, void* d_ws, size_t ws_size,
                              hipStream_t stream) {
  const float* x  = (const float*)d_in[0];
  const float* S0 = (const float*)d_in[1];
  const float* Wk = (const float*)d_in[2];
  const float* Wv = (const float*)d_in[3];
  const float* Wq = (const float*)d_in[4];
  const float* Wa = (const float*)d_in[5];
  const float* da = (const float*)d_in[6];
  const float* ba = (const float*)d_in[7];

  float* out  = (float*)d_out;                        // [T,B,64]
  float* Sout = out + (size_t)T_STEPS * BATCH * NST;  // [B,64,64]
  _Float16* P = (_Float16*)d_ws;                      // 2 x [16384][256] f16 = 16 MB
  _Float16* Wc = (_Float16*)((char*)d_ws + (size_t)16 * 1024 * 1024);  // 512 KB

  wconv<<<256, 256, 0, stream>>>(Wk, Wv, Wq, Wa, Wc);
  dim3 ggrid(16384 / 64, 2);
  proj_gemm<<<ggrid, 256, 0, stream>>>(x, Wc, P);
  scan_kernel<<<4 * BATCH, 256, 0, stream>>>(P, P + (size_t)16384 * 256, S0, da, ba,
                                             out, Sout);
}